// Round 5
// baseline (353.552 us; speedup 1.0000x reference)
//
#include <hip/hip_runtime.h>
#include <cstdint>

// Problem constants: B=4, T=2048, D=1024, H=16, hd=64
#define MFMA16(a, b, c) __builtin_amdgcn_mfma_f32_16x16x32_bf16(a, b, c, 0, 0, 0)
#define MFMA32(a, b, c) __builtin_amdgcn_mfma_f32_32x32x16_bf16(a, b, c, 0, 0, 0)

typedef float  f32x4   __attribute__((ext_vector_type(4)));
typedef float  f32x16  __attribute__((ext_vector_type(16)));
typedef __bf16 bf16x8  __attribute__((ext_vector_type(8)));

__device__ __forceinline__ void gload_lds16(const void* g, const void* l) {
  __builtin_amdgcn_global_load_lds(
      (const __attribute__((address_space(1))) unsigned int*)(uintptr_t)g,
      (__attribute__((address_space(3))) unsigned int*)(unsigned int)(uintptr_t)l,
      16, 0, 0);
}

__device__ __forceinline__ uint32_t pack_bf16(float a, float b) {
  union { __bf16 h[2]; uint32_t u; } u;
  u.h[0] = (__bf16)a; u.h[1] = (__bf16)b;
  return u.u;
}

__device__ __forceinline__ float fexp2(float x) { return __builtin_amdgcn_exp2f(x); }

// ---------------- fp32 -> bf16 convert (vectorized) ----------------
__global__ void k_cvt(const float* __restrict__ in, __bf16* __restrict__ out, int n4) {
  int i = blockIdx.x * 256 + threadIdx.x;
  if (i >= n4) return;
  float4 v = reinterpret_cast<const float4*>(in)[i];
  __bf16 o[4] = {(__bf16)v.x, (__bf16)v.y, (__bf16)v.z, (__bf16)v.w};
  *reinterpret_cast<uint2*>(out + (size_t)i * 4) = *reinterpret_cast<const uint2*>(o);
}

// ---------------- fp32 [R][C] -> bf16 [C][R] tiled transpose ----------------
__global__ void k_transpose(const float* __restrict__ in, __bf16* __restrict__ out,
                            int R, int C) {
  __shared__ float tile[32][33];
  const int c0 = blockIdx.x * 32, r0 = blockIdx.y * 32;
  const int x = threadIdx.x & 31, y = threadIdx.x >> 5;
#pragma unroll
  for (int i = 0; i < 4; ++i)
    tile[y + i * 8][x] = in[(size_t)(r0 + y + i * 8) * C + c0 + x];
  __syncthreads();
#pragma unroll
  for (int i = 0; i < 4; ++i)
    out[(size_t)(c0 + y + i * 8) * R + r0 + x] = (__bf16)tile[x][y + i * 8];
}

// ---------------- GEMM1: qkv = x @ W_attn + b_attn, scattered to Q/K/VT ----------------
// Q pre-scaled by (1/sqrt(64))*log2(e). blockIdx.x>>3 selects output: 0=Q 1=K 2=V.
// V written transposed via LDS roundtrip -> fully coalesced dwordx4 stores.
__global__ __launch_bounds__(256) void k_gemm_qkv(
    const __bf16* __restrict__ A, const __bf16* __restrict__ Bt,
    const float* __restrict__ bias,
    __bf16* __restrict__ Qg, __bf16* __restrict__ Kg, __bf16* __restrict__ VTg) {
  __shared__ __align__(16) char GS[16384];
  __bf16* As = (__bf16*)GS;
  __bf16* Bs = (__bf16*)(GS + 8192);
  const int tid = threadIdx.x;
  const int w = tid >> 6, l = tid & 63;
  const int l15 = l & 15, quad = l >> 4;
  const int wr = w >> 1, wc = w & 1;
  const int bm0 = blockIdx.y * 128, bn0 = blockIdx.x * 128;
  const int which = blockIdx.x >> 3;  // 0 Q, 1 K, 2 V (block-uniform)
  const float SC = 0.18033688011112042f;

  const int rs = w * 32 + (l >> 2);
  const int kc = (l & 3) * 8;
  const __bf16* gA = A + (size_t)(bm0 + rs) * 1024 + kc;
  const __bf16* gB = Bt + (size_t)(bn0 + rs) * 1024 + kc;

  f32x4 acc[4][4] = {};

  for (int k0 = 0; k0 < 1024; k0 += 32) {
    gload_lds16(gA + k0,             As + w * 1024);
    gload_lds16(gA + k0 + 16 * 1024, As + w * 1024 + 512);
    gload_lds16(gB + k0,             Bs + w * 1024);
    gload_lds16(gB + k0 + 16 * 1024, Bs + w * 1024 + 512);
    __syncthreads();
    bf16x8 af[4], bv[4];
#pragma unroll
    for (int mt = 0; mt < 4; ++mt)
      af[mt] = *(const bf16x8*)(As + (wr * 64 + mt * 16 + l15) * 32 + quad * 8);
#pragma unroll
    for (int nt = 0; nt < 4; ++nt)
      bv[nt] = *(const bf16x8*)(Bs + (wc * 64 + nt * 16 + l15) * 32 + quad * 8);
#pragma unroll
    for (int mt = 0; mt < 4; ++mt)
#pragma unroll
      for (int nt = 0; nt < 4; ++nt)
        acc[mt][nt] = MFMA16(af[mt], bv[nt], acc[mt][nt]);
    __syncthreads();
  }

  if (which < 2) {
    __bf16* dst = which == 0 ? Qg : Kg;
    const float mul = which == 0 ? SC : 1.0f;
#pragma unroll
    for (int nt = 0; nt < 4; ++nt) {
      const int n = bn0 + wc * 64 + nt * 16 + l15;
      const float bvv = bias[n];
      const int rem = n & 1023;
      const int hh = rem >> 6, dh = rem & 63;
#pragma unroll
      for (int mt = 0; mt < 4; ++mt) {
#pragma unroll
        for (int r = 0; r < 4; ++r) {
          const int m = bm0 + wr * 64 + mt * 16 + quad * 4 + r;
          const int bb = m >> 11, t = m & 2047;
          dst[(((size_t)(bb * 16 + hh)) * 2048 + t) * 64 + dh] =
              (__bf16)((acc[mt][nt][r] + bvv) * mul);
        }
      }
    }
  } else {
    // V: LDS transpose. VLs: [64 n_local][32 m-chunks of 8B, XOR-swizzled]
    __bf16* VLs = (__bf16*)GS;
    const int bbq = bm0 >> 11;          // batch index (bm0 spans one b)
    const int tloc = bm0 & 2047;
#pragma unroll
    for (int h2 = 0; h2 < 2; ++h2) {
      __syncthreads();
      if (wc == h2) {
#pragma unroll
        for (int nt = 0; nt < 4; ++nt) {
          const int nl = nt * 16 + l15;
          const float bvv = bias[bn0 + wc * 64 + nt * 16 + l15];
#pragma unroll
          for (int mt = 0; mt < 4; ++mt) {
            const int cm = wr * 16 + mt * 4 + quad;          // 8B chunk of m (0..31)
            const int cs = (cm & 16) | ((cm & 15) ^ l15);    // swizzled slot
            uint2 pkv;
            pkv.x = pack_bf16(acc[mt][nt][0] + bvv, acc[mt][nt][1] + bvv);
            pkv.y = pack_bf16(acc[mt][nt][2] + bvv, acc[mt][nt][3] + bvv);
            *(uint2*)(VLs + nl * 128 + cs * 4) = pkv;
          }
        }
      }
      __syncthreads();
      // readout: 64 rows x 16 x 16B chunks; thread -> (n_local, chunk)
      const int nl = tid >> 2;
      const int ng = bn0 + h2 * 64 + nl;        // global qkv column
      const int v = ng - 2048;                  // v-feature 0..1023
      const int bhd = bbq * 16 + (v >> 6), dh = v & 63;
      __bf16* vrow = VTg + ((size_t)bhd * 64 + dh) * 2048;
#pragma unroll
      for (int p2 = 0; p2 < 4; ++p2) {
        const int c16 = (tid & 3) + p2 * 4;
        const int g0 = 2 * c16, g1 = g0 + 1;
        const int s0 = (g0 & 16) | ((g0 & 15) ^ (nl & 15));
        const int s1 = (g1 & 16) | ((g1 & 15) ^ (nl & 15));
        uint2 a = *(const uint2*)(VLs + nl * 128 + s0 * 4);
        uint2 b = *(const uint2*)(VLs + nl * 128 + s1 * 4);
        uint4 val = {a.x, a.y, b.x, b.y};
        *(uint4*)(vrow + tloc + c16 * 8) = val;
      }
    }
  }
}

// ---------------- Flash attention: 8 waves, split-kv, 32x32 MFMA ----------------
// Grid (64, 8), 512 threads. Block handles q-tiles {p, 15-p} for bh=blockIdx.x.
// Waves: wq = w&3 (q sub-tile of 32 rows), hf = w>>2 (kv half). Each barrier
// interval stages 128 kv rows (two 64-tiles); half hf computes tile 2j+hf.
// Fixed-max softmax (exact by shift-invariance) -> split-kv merge is a pure add.
__global__ __launch_bounds__(512, 4) void k_attn(
    const __bf16* __restrict__ Qg, const __bf16* __restrict__ Kg,
    const __bf16* __restrict__ VTg, __bf16* __restrict__ yb) {
  __shared__ __align__(16) char smem[66560];
  // K: smem[b*16384], [128 kv][64 d], 16B chunks swizzled by (row&7)
  // V: smem[32768 + b*16384], [64 d][128 t], 16B slots: (g&8)|((g&7)^(d&7))
  // merge: reuse smem[0..32768) as float4[8][4][64]; Ls2 at 65536: float[4][64]
  const int tid = threadIdx.x;
  const int w = tid >> 6, l = tid & 63;
  const int wq = w & 3, hf = w >> 2, wqh = wq >> 1;
  const int l31 = l & 31, cH = l >> 5;
  const int bh = blockIdx.x;
  const int bb = bh >> 4, h = bh & 15;
  const __bf16* Qb = Qg + (size_t)bh * 2048 * 64;

  // staging addresses
  const int rk = w * 8 + (l >> 3);                 // K row 0..63 (call A; B:+64)
  const __bf16* gK = Kg + ((size_t)bh * 2048 + rk) * 64 + (((l & 7) ^ (rk & 7)) * 8);
  const int rv = w * 4 + (l >> 4);                 // V row 0..31 (call A; B:+32)
  const int rvB = rv + 32;
  const __bf16* gVA = VTg + ((size_t)bh * 64 + rv) * 2048 +
                      (((l & 8) | ((l & 7) ^ (rv & 7))) * 8);
  const __bf16* gVB = VTg + ((size_t)bh * 64 + rvB) * 2048 +
                      (((l & 8) | ((l & 7) ^ (rvB & 7))) * 8);

  for (int seg = 0; seg < 2; ++seg) {
    const int p = seg ? 15 - blockIdx.y : blockIdx.y;
    const int qt0 = p * 128 + wq * 32;
    const int q = qt0 + l31;

    __syncthreads();  // LDS free (prev seg merge / staging done)

    // Q B-fragments (pre-scaled): k = s*16 + cH*8 + j
    bf16x8 qf[4];
#pragma unroll
    for (int s = 0; s < 4; ++s)
      qf[s] = *(const bf16x8*)(Qb + (size_t)q * 64 + s * 16 + cH * 8);

    f32x16 o0 = {}, o1 = {};
    float lsum = 0.f;

    // prefetch interval 0 -> buf 0
    {
      char* KSb = smem;
      char* VSb = smem + 32768;
      gload_lds16(gK,           KSb + w * 1024);
      gload_lds16(gK + 64 * 64, KSb + 8192 + w * 1024);
      gload_lds16(gVA,          VSb + w * 1024);
      gload_lds16(gVB,          VSb + 8192 + w * 1024);
    }

    for (int j = 0; j <= p; ++j) {
      __syncthreads();  // buf(j&1) staged
      if (j < p) {
        const int b2 = (j + 1) & 1;
        char* KSb = smem + b2 * 16384;
        char* VSb = smem + 32768 + b2 * 16384;
        const size_t ko = (size_t)(128 * (j + 1)) * 64;
        gload_lds16(gK + ko,           KSb + w * 1024);
        gload_lds16(gK + ko + 64 * 64, KSb + 8192 + w * 1024);
        gload_lds16(gVA + 128 * (j + 1), VSb + w * 1024);
        gload_lds16(gVB + 128 * (j + 1), VSb + 8192 + w * 1024);
      }
      const bool act = (j < p) || (hf <= wqh);
      if (act) {
        const bool diag = (j == p) && (hf == wqh);
        const int b = j & 1;
        const __bf16* KSb = (const __bf16*)(smem + b * 16384);
        const __bf16* VSb = (const __bf16*)(smem + 32768 + b * 16384);
        const int kv0 = (2 * j + hf) * 64;
        const int R0 = 64 * hf + l31;   // K region row for st0; st1: +32

        bf16x8 kf0[4], kf1[4];
#pragma unroll
        for (int s = 0; s < 4; ++s) {
          const int c = ((2 * s + cH) ^ (R0 & 7)) * 8;
          kf0[s] = *(const bf16x8*)(KSb + R0 * 64 + c);
          kf1[s] = *(const bf16x8*)(KSb + (R0 + 32) * 64 + c);
        }
        f32x16 st0 = {}, st1 = {};
#pragma unroll
        for (int s = 0; s < 4; ++s) st0 = MFMA32(kf0[s], qf[s], st0);
#pragma unroll
        for (int s = 0; s < 4; ++s) st1 = MFMA32(kf1[s], qf[s], st1);

        if (diag) {
          const int base0 = kv0 + 4 * cH;
          const int base1 = kv0 + 32 + 4 * cH;
#pragma unroll
          for (int r = 0; r < 16; ++r) {
            const int off = (r & 3) + 8 * (r >> 2);
            if (base0 + off > q) st0[r] = -1e30f;
            if (base1 + off > q) st1[r] = -1e30f;
          }
        }

        // exp2 (fixed max 0), pairwise-tree sum, pack to bf16 dwords
        uint32_t pk[2][4][2];
        float sacc[2];
#pragma unroll
        for (int kvt = 0; kvt < 2; ++kvt) {
          float pp[16];
#pragma unroll
          for (int r = 0; r < 16; ++r) pp[r] = fexp2(kvt ? st1[r] : st0[r]);
          float s01 = (pp[0] + pp[1]) + (pp[2] + pp[3]);
          float s23 = (pp[4] + pp[5]) + (pp[6] + pp[7]);
          float s45 = (pp[8] + pp[9]) + (pp[10] + pp[11]);
          float s67 = (pp[12] + pp[13]) + (pp[14] + pp[15]);
          sacc[kvt] = (s01 + s23) + (s45 + s67);
#pragma unroll
          for (int rq = 0; rq < 4; ++rq) {
            pk[kvt][rq][0] = pack_bf16(pp[4 * rq], pp[4 * rq + 1]);
            pk[kvt][rq][1] = pack_bf16(pp[4 * rq + 2], pp[4 * rq + 3]);
          }
        }
        lsum += sacc[0] + sacc[1];

        // V^T A-fragments
        bf16x8 vf0[4], vf1[4];
#pragma unroll
        for (int s = 0; s < 4; ++s) {
          const int sl0 = (8 * hf) | ((2 * s + cH) ^ (l31 & 7));
          vf0[s] = *(const bf16x8*)(VSb + l31 * 128 + sl0 * 8);
          vf1[s] = *(const bf16x8*)(VSb + (32 + l31) * 128 + sl0 * 8);
        }

        // PV: B-frag via pack + one xor-32 swap per k-step
#pragma unroll
        for (int s = 0; s < 4; ++s) {
          const int kvt = s >> 1;
          const int rq_own = 2 * (s & 1) + cH;
          const int rq_snd = 2 * (s & 1) + 1 - cH;
          const uint32_t own0 = pk[kvt][rq_own][0], own1 = pk[kvt][rq_own][1];
          const uint32_t rcv0 = (uint32_t)__shfl_xor((int)pk[kvt][rq_snd][0], 32, 64);
          const uint32_t rcv1 = (uint32_t)__shfl_xor((int)pk[kvt][rq_snd][1], 32, 64);
          union { uint32_t u[4]; bf16x8 v; } pf;
          pf.u[0] = cH ? rcv0 : own0;
          pf.u[1] = cH ? rcv1 : own1;
          pf.u[2] = cH ? own0 : rcv0;
          pf.u[3] = cH ? own1 : rcv1;
          o0 = MFMA32(vf0[s], pf.v, o0);
          o1 = MFMA32(vf1[s], pf.v, o1);
        }
      }
    }

    // split-kv merge: half1 writes (o, sum) to LDS; half0 combines and stores y
    __syncthreads();
    float4* Msh = (float4*)smem;
    float* Ls2 = (float*)(smem + 65536);
    const float stot = lsum + __shfl_xor(lsum, 32, 64);
    union { f32x16 v; float4 q4[4]; } u0, u1;
    u0.v = o0; u1.v = o1;
    if (hf == 1) {
#pragma unroll
      for (int i = 0; i < 4; ++i) {
        Msh[(i * 4 + wq) * 64 + l] = u0.q4[i];
        Msh[((i + 4) * 4 + wq) * 64 + l] = u1.q4[i];
      }
      Ls2[wq * 64 + l] = stot;
    }
    __syncthreads();
    if (hf == 0) {
#pragma unroll
      for (int i = 0; i < 4; ++i) {
        float4 a = Msh[(i * 4 + wq) * 64 + l];
        float4 b2 = Msh[((i + 4) * 4 + wq) * 64 + l];
        u0.q4[i].x += a.x; u0.q4[i].y += a.y; u0.q4[i].z += a.z; u0.q4[i].w += a.w;
        u1.q4[i].x += b2.x; u1.q4[i].y += b2.y; u1.q4[i].z += b2.z; u1.q4[i].w += b2.w;
      }
      const float inv = 1.0f / (stot + Ls2[wq * 64 + l]);
      __bf16* yrow = yb + ((size_t)(bb * 2048 + q)) * 1024 + h * 64;
#pragma unroll
      for (int dt = 0; dt < 2; ++dt) {
        const f32x16& o = dt ? u1.v : u0.v;
#pragma unroll
        for (int rq = 0; rq < 4; ++rq) {
          __bf16 ov[4];
#pragma unroll
          for (int i = 0; i < 4; ++i) ov[i] = (__bf16)(o[4 * rq + i] * inv);
          *(uint2*)(yrow + dt * 32 + 8 * rq + 4 * cH) = *(uint2*)ov;
        }
      }
    }
  }
}

// ---------------- GEMM2: out = y @ W_proj + b_proj (fp32 out) ----------------
__global__ __launch_bounds__(256) void k_gemm_proj(
    const __bf16* __restrict__ A, const __bf16* __restrict__ Bt,
    const float* __restrict__ bias, float* __restrict__ out) {
  __shared__ __align__(16) __bf16 As[128 * 32];
  __shared__ __align__(16) __bf16 Bs[128 * 32];
  const int tid = threadIdx.x;
  const int w = tid >> 6, l = tid & 63;
  const int l15 = l & 15, quad = l >> 4;
  const int wr = w >> 1, wc = w & 1;
  const int bm0 = blockIdx.y * 128, bn0 = blockIdx.x * 128;

  const int rs = w * 32 + (l >> 2);
  const int kc = (l & 3) * 8;
  const __bf16* gA = A + (size_t)(bm0 + rs) * 1024 + kc;
  const __bf16* gB = Bt + (size_t)(bn0 + rs) * 1024 + kc;

  f32x4 acc[4][4] = {};

  for (int k0 = 0; k0 < 1024; k0 += 32) {
    gload_lds16(gA + k0,             As + w * 1024);
    gload_lds16(gA + k0 + 16 * 1024, As + w * 1024 + 512);
    gload_lds16(gB + k0,             Bs + w * 1024);
    gload_lds16(gB + k0 + 16 * 1024, Bs + w * 1024 + 512);
    __syncthreads();
    bf16x8 af[4], bv[4];
#pragma unroll
    for (int mt = 0; mt < 4; ++mt)
      af[mt] = *(const bf16x8*)(As + (wr * 64 + mt * 16 + l15) * 32 + quad * 8);
#pragma unroll
    for (int nt = 0; nt < 4; ++nt)
      bv[nt] = *(const bf16x8*)(Bs + (wc * 64 + nt * 16 + l15) * 32 + quad * 8);
#pragma unroll
    for (int mt = 0; mt < 4; ++mt)
#pragma unroll
      for (int nt = 0; nt < 4; ++nt)
        acc[mt][nt] = MFMA16(af[mt], bv[nt], acc[mt][nt]);
    __syncthreads();
  }

#pragma unroll
  for (int nt = 0; nt < 4; ++nt) {
    const int n = bn0 + wc * 64 + nt * 16 + l15;
    const float bvv = bias[n];
#pragma unroll
    for (int mt = 0; mt < 4; ++mt) {
#pragma unroll
      for (int r = 0; r < 4; ++r) {
        const int m = bm0 + wr * 64 + mt * 16 + quad * 4 + r;
        out[(size_t)m * 1024 + n] = acc[mt][nt][r] + bvv;
      }
    }
  }
}

extern "C" void kernel_launch(void* const* d_in, const int* in_sizes, int n_in,
                              void* d_out, int out_size, void* d_ws, size_t ws_size,
                              hipStream_t stream) {
  const float* x      = (const float*)d_in[0];
  const float* W_attn = (const float*)d_in[1];
  const float* b_attn = (const float*)d_in[2];
  const float* W_proj = (const float*)d_in[3];
  const float* b_proj = (const float*)d_in[4];
  float* out = (float*)d_out;
  char* ws = (char*)d_ws;

  __bf16* xb  = (__bf16*)(ws);                     // 16 MiB  x bf16; later reused as y
  __bf16* WaT = (__bf16*)(ws + (16ull << 20));     //  6 MiB  W_attn^T bf16
  __bf16* WpT = (__bf16*)(ws + (22ull << 20));     //  2 MiB  W_proj^T bf16
  __bf16* Qg  = (__bf16*)(ws + (24ull << 20));     // 16 MiB  Q*SC [bh][T][64]
  __bf16* Kg  = (__bf16*)(ws + (40ull << 20));     // 16 MiB  K [bh][T][64]
  __bf16* VTg = (__bf16*)(ws + (56ull << 20));     // 16 MiB  V^T [bh][64][T]

  k_cvt<<<8192, 256, 0, stream>>>(x, xb, 2097152);
  k_transpose<<<dim3(96, 32), 256, 0, stream>>>(W_attn, WaT, 1024, 3072);
  k_transpose<<<dim3(32, 32), 256, 0, stream>>>(W_proj, WpT, 1024, 1024);
  k_gemm_qkv<<<dim3(24, 64), 256, 0, stream>>>(xb, WaT, b_attn, Qg, Kg, VTg);
  k_attn<<<dim3(64, 8), 512, 0, stream>>>(Qg, Kg, VTg, xb /* y reuses xb */);
  k_gemm_proj<<<dim3(8, 64), 256, 0, stream>>>(xb, WpT, b_proj, out);
}

// Round 6
// 317.485 us; speedup vs baseline: 1.1136x; 1.1136x over previous
//
#include <hip/hip_runtime.h>
#include <cstdint>

// Problem constants: B=4, T=2048, D=1024, H=16, hd=64
#define MFMA16(a, b, c) __builtin_amdgcn_mfma_f32_16x16x32_bf16(a, b, c, 0, 0, 0)
#define MFMA32(a, b, c) __builtin_amdgcn_mfma_f32_32x32x16_bf16(a, b, c, 0, 0, 0)

typedef float  f32x4   __attribute__((ext_vector_type(4)));
typedef float  f32x16  __attribute__((ext_vector_type(16)));
typedef __bf16 bf16x8  __attribute__((ext_vector_type(8)));

__device__ __forceinline__ void gload_lds16(const void* g, const void* l) {
  __builtin_amdgcn_global_load_lds(
      (const __attribute__((address_space(1))) unsigned int*)(uintptr_t)g,
      (__attribute__((address_space(3))) unsigned int*)(unsigned int)(uintptr_t)l,
      16, 0, 0);
}

__device__ __forceinline__ uint32_t pack_bf16(float a, float b) {
  union { __bf16 h[2]; uint32_t u; } u;
  u.h[0] = (__bf16)a; u.h[1] = (__bf16)b;
  return u.u;
}

__device__ __forceinline__ float fexp2(float x) { return __builtin_amdgcn_exp2f(x); }

// ---------------- fp32 -> bf16 convert (vectorized) ----------------
__global__ void k_cvt(const float* __restrict__ in, __bf16* __restrict__ out, int n4) {
  int i = blockIdx.x * 256 + threadIdx.x;
  if (i >= n4) return;
  float4 v = reinterpret_cast<const float4*>(in)[i];
  __bf16 o[4] = {(__bf16)v.x, (__bf16)v.y, (__bf16)v.z, (__bf16)v.w};
  *reinterpret_cast<uint2*>(out + (size_t)i * 4) = *reinterpret_cast<const uint2*>(o);
}

// ---------------- fp32 [R][C] -> bf16 [C][R] tiled transpose ----------------
__global__ void k_transpose(const float* __restrict__ in, __bf16* __restrict__ out,
                            int R, int C) {
  __shared__ float tile[32][33];
  const int c0 = blockIdx.x * 32, r0 = blockIdx.y * 32;
  const int x = threadIdx.x & 31, y = threadIdx.x >> 5;
#pragma unroll
  for (int i = 0; i < 4; ++i)
    tile[y + i * 8][x] = in[(size_t)(r0 + y + i * 8) * C + c0 + x];
  __syncthreads();
#pragma unroll
  for (int i = 0; i < 4; ++i)
    out[(size_t)(c0 + y + i * 8) * R + r0 + x] = (__bf16)tile[x][y + i * 8];
}

// ---------------- GEMM1: qkv = x @ W_attn + b_attn, scattered to Q/K/VT ----------------
// Q pre-scaled by (1/sqrt(64))*log2(e). blockIdx.x>>3 selects output: 0=Q 1=K 2=V.
// V written transposed via LDS roundtrip -> fully coalesced dwordx4 stores.
__global__ __launch_bounds__(256) void k_gemm_qkv(
    const __bf16* __restrict__ A, const __bf16* __restrict__ Bt,
    const float* __restrict__ bias,
    __bf16* __restrict__ Qg, __bf16* __restrict__ Kg, __bf16* __restrict__ VTg) {
  __shared__ __align__(16) char GS[16384];
  __bf16* As = (__bf16*)GS;
  __bf16* Bs = (__bf16*)(GS + 8192);
  const int tid = threadIdx.x;
  const int w = tid >> 6, l = tid & 63;
  const int l15 = l & 15, quad = l >> 4;
  const int wr = w >> 1, wc = w & 1;
  const int bm0 = blockIdx.y * 128, bn0 = blockIdx.x * 128;
  const int which = blockIdx.x >> 3;  // 0 Q, 1 K, 2 V (block-uniform)
  const float SC = 0.18033688011112042f;

  const int rs = w * 32 + (l >> 2);
  const int kc = (l & 3) * 8;
  const __bf16* gA = A + (size_t)(bm0 + rs) * 1024 + kc;
  const __bf16* gB = Bt + (size_t)(bn0 + rs) * 1024 + kc;

  f32x4 acc[4][4] = {};

  for (int k0 = 0; k0 < 1024; k0 += 32) {
    gload_lds16(gA + k0,             As + w * 1024);
    gload_lds16(gA + k0 + 16 * 1024, As + w * 1024 + 512);
    gload_lds16(gB + k0,             Bs + w * 1024);
    gload_lds16(gB + k0 + 16 * 1024, Bs + w * 1024 + 512);
    __syncthreads();
    bf16x8 af[4], bv[4];
#pragma unroll
    for (int mt = 0; mt < 4; ++mt)
      af[mt] = *(const bf16x8*)(As + (wr * 64 + mt * 16 + l15) * 32 + quad * 8);
#pragma unroll
    for (int nt = 0; nt < 4; ++nt)
      bv[nt] = *(const bf16x8*)(Bs + (wc * 64 + nt * 16 + l15) * 32 + quad * 8);
#pragma unroll
    for (int mt = 0; mt < 4; ++mt)
#pragma unroll
      for (int nt = 0; nt < 4; ++nt)
        acc[mt][nt] = MFMA16(af[mt], bv[nt], acc[mt][nt]);
    __syncthreads();
  }

  if (which < 2) {
    __bf16* dst = which == 0 ? Qg : Kg;
    const float mul = which == 0 ? SC : 1.0f;
#pragma unroll
    for (int nt = 0; nt < 4; ++nt) {
      const int n = bn0 + wc * 64 + nt * 16 + l15;
      const float bvv = bias[n];
      const int rem = n & 1023;
      const int hh = rem >> 6, dh = rem & 63;
#pragma unroll
      for (int mt = 0; mt < 4; ++mt) {
#pragma unroll
        for (int r = 0; r < 4; ++r) {
          const int m = bm0 + wr * 64 + mt * 16 + quad * 4 + r;
          const int bb = m >> 11, t = m & 2047;
          dst[(((size_t)(bb * 16 + hh)) * 2048 + t) * 64 + dh] =
              (__bf16)((acc[mt][nt][r] + bvv) * mul);
        }
      }
    }
  } else {
    // V: LDS transpose. VLs: [64 n_local][32 m-chunks of 8B, XOR-swizzled]
    __bf16* VLs = (__bf16*)GS;
    const int bbq = bm0 >> 11;          // batch index (bm0 spans one b)
    const int tloc = bm0 & 2047;
#pragma unroll
    for (int h2 = 0; h2 < 2; ++h2) {
      __syncthreads();
      if (wc == h2) {
#pragma unroll
        for (int nt = 0; nt < 4; ++nt) {
          const int nl = nt * 16 + l15;
          const float bvv = bias[bn0 + wc * 64 + nt * 16 + l15];
#pragma unroll
          for (int mt = 0; mt < 4; ++mt) {
            const int cm = wr * 16 + mt * 4 + quad;          // 8B chunk of m (0..31)
            const int cs = (cm & 16) | ((cm & 15) ^ l15);    // swizzled slot
            uint2 pkv;
            pkv.x = pack_bf16(acc[mt][nt][0] + bvv, acc[mt][nt][1] + bvv);
            pkv.y = pack_bf16(acc[mt][nt][2] + bvv, acc[mt][nt][3] + bvv);
            *(uint2*)(VLs + nl * 128 + cs * 4) = pkv;
          }
        }
      }
      __syncthreads();
      // readout: 64 rows x 16 x 16B chunks; thread -> (n_local, chunk)
      const int nl = tid >> 2;
      const int ng = bn0 + h2 * 64 + nl;        // global qkv column
      const int v = ng - 2048;                  // v-feature 0..1023
      const int bhd = bbq * 16 + (v >> 6), dh = v & 63;
      __bf16* vrow = VTg + ((size_t)bhd * 64 + dh) * 2048;
#pragma unroll
      for (int p2 = 0; p2 < 4; ++p2) {
        const int c16 = (tid & 3) + p2 * 4;
        const int g0 = 2 * c16, g1 = g0 + 1;
        const int s0 = (g0 & 16) | ((g0 & 15) ^ (nl & 15));
        const int s1 = (g1 & 16) | ((g1 & 15) ^ (nl & 15));
        uint2 a = *(const uint2*)(VLs + nl * 128 + s0 * 4);
        uint2 b = *(const uint2*)(VLs + nl * 128 + s1 * 4);
        uint4 val = {a.x, a.y, b.x, b.y};
        *(uint4*)(vrow + tloc + c16 * 8) = val;
      }
    }
  }
}

// ---------------- Flash attention: 8 waves, split-kv, 32x32 MFMA ----------------
// Grid (64, 8), 512 threads. Block handles q-tiles {p, 15-p} for bh=blockIdx.x.
// Waves: wq = w&3 (q sub-tile of 32 rows), hf = w>>2 (kv half). Each barrier
// interval stages 128 kv rows (two 64-tiles); half hf computes tile 2j+hf.
// Fixed-max softmax (exact by shift-invariance) -> split-kv merge is a pure add.
// NOTE: __launch_bounds__(512) ONLY — R5's (512,4) min-occupancy request forced
// VGPR<=64 and spilled the f32x16 accumulators to scratch (FETCH 25->154MB).
__global__ __launch_bounds__(512) void k_attn(
    const __bf16* __restrict__ Qg, const __bf16* __restrict__ Kg,
    const __bf16* __restrict__ VTg, __bf16* __restrict__ yb) {
  __shared__ __align__(16) char smem[66560];
  // K: smem[b*16384], [128 kv][64 d], 16B chunks swizzled by (row&7)
  // V: smem[32768 + b*16384], [64 d][128 t], 16B slots: (g&8)|((g&7)^(d&7))
  // merge: reuse smem[0..32768) as float4[8][4][64]; Ls2 at 65536: float[4][64]
  const int tid = threadIdx.x;
  const int w = tid >> 6, l = tid & 63;
  const int wq = w & 3, hf = w >> 2, wqh = wq >> 1;
  const int l31 = l & 31, cH = l >> 5;
  const int bh = blockIdx.x;
  const int bb = bh >> 4, h = bh & 15;
  const __bf16* Qb = Qg + (size_t)bh * 2048 * 64;

  // staging addresses
  const int rk = w * 8 + (l >> 3);                 // K row 0..63 (call A; B:+64)
  const __bf16* gK = Kg + ((size_t)bh * 2048 + rk) * 64 + (((l & 7) ^ (rk & 7)) * 8);
  const int rv = w * 4 + (l >> 4);                 // V row 0..31 (call A; B:+32)
  const int rvB = rv + 32;
  const __bf16* gVA = VTg + ((size_t)bh * 64 + rv) * 2048 +
                      (((l & 8) | ((l & 7) ^ (rv & 7))) * 8);
  const __bf16* gVB = VTg + ((size_t)bh * 64 + rvB) * 2048 +
                      (((l & 8) | ((l & 7) ^ (rvB & 7))) * 8);

  for (int seg = 0; seg < 2; ++seg) {
    const int p = seg ? 15 - blockIdx.y : blockIdx.y;
    const int qt0 = p * 128 + wq * 32;
    const int q = qt0 + l31;

    __syncthreads();  // LDS free (prev seg merge / staging done)

    // Q B-fragments (pre-scaled): k = s*16 + cH*8 + j
    bf16x8 qf[4];
#pragma unroll
    for (int s = 0; s < 4; ++s)
      qf[s] = *(const bf16x8*)(Qb + (size_t)q * 64 + s * 16 + cH * 8);

    f32x16 o0 = {}, o1 = {};
    float lsum = 0.f;

    // prefetch interval 0 -> buf 0
    {
      char* KSb = smem;
      char* VSb = smem + 32768;
      gload_lds16(gK,           KSb + w * 1024);
      gload_lds16(gK + 64 * 64, KSb + 8192 + w * 1024);
      gload_lds16(gVA,          VSb + w * 1024);
      gload_lds16(gVB,          VSb + 8192 + w * 1024);
    }

    for (int j = 0; j <= p; ++j) {
      __syncthreads();  // buf(j&1) staged
      if (j < p) {
        const int b2 = (j + 1) & 1;
        char* KSb = smem + b2 * 16384;
        char* VSb = smem + 32768 + b2 * 16384;
        const size_t ko = (size_t)(128 * (j + 1)) * 64;
        gload_lds16(gK + ko,           KSb + w * 1024);
        gload_lds16(gK + ko + 64 * 64, KSb + 8192 + w * 1024);
        gload_lds16(gVA + 128 * (j + 1), VSb + w * 1024);
        gload_lds16(gVB + 128 * (j + 1), VSb + 8192 + w * 1024);
      }
      const bool act = (j < p) || (hf <= wqh);
      if (act) {
        const bool diag = (j == p) && (hf == wqh);
        const int b = j & 1;
        const __bf16* KSb = (const __bf16*)(smem + b * 16384);
        const __bf16* VSb = (const __bf16*)(smem + 32768 + b * 16384);
        const int kv0 = (2 * j + hf) * 64;
        const int R0 = 64 * hf + l31;   // K region row for st0; st1: +32

        bf16x8 kf0[4], kf1[4];
#pragma unroll
        for (int s = 0; s < 4; ++s) {
          const int c = ((2 * s + cH) ^ (R0 & 7)) * 8;
          kf0[s] = *(const bf16x8*)(KSb + R0 * 64 + c);
          kf1[s] = *(const bf16x8*)(KSb + (R0 + 32) * 64 + c);
        }
        f32x16 st0 = {}, st1 = {};
#pragma unroll
        for (int s = 0; s < 4; ++s) st0 = MFMA32(kf0[s], qf[s], st0);
#pragma unroll
        for (int s = 0; s < 4; ++s) st1 = MFMA32(kf1[s], qf[s], st1);

        if (diag) {
          const int base0 = kv0 + 4 * cH;
          const int base1 = kv0 + 32 + 4 * cH;
#pragma unroll
          for (int r = 0; r < 16; ++r) {
            const int off = (r & 3) + 8 * (r >> 2);
            if (base0 + off > q) st0[r] = -1e30f;
            if (base1 + off > q) st1[r] = -1e30f;
          }
        }

        // exp2 (fixed max 0), pairwise-tree sum, pack to bf16 dwords
        uint32_t pk[2][4][2];
        float sacc[2];
#pragma unroll
        for (int kvt = 0; kvt < 2; ++kvt) {
          float pp[16];
#pragma unroll
          for (int r = 0; r < 16; ++r) pp[r] = fexp2(kvt ? st1[r] : st0[r]);
          float s01 = (pp[0] + pp[1]) + (pp[2] + pp[3]);
          float s23 = (pp[4] + pp[5]) + (pp[6] + pp[7]);
          float s45 = (pp[8] + pp[9]) + (pp[10] + pp[11]);
          float s67 = (pp[12] + pp[13]) + (pp[14] + pp[15]);
          sacc[kvt] = (s01 + s23) + (s45 + s67);
#pragma unroll
          for (int rq = 0; rq < 4; ++rq) {
            pk[kvt][rq][0] = pack_bf16(pp[4 * rq], pp[4 * rq + 1]);
            pk[kvt][rq][1] = pack_bf16(pp[4 * rq + 2], pp[4 * rq + 3]);
          }
        }
        lsum += sacc[0] + sacc[1];

        // V^T A-fragments
        bf16x8 vf0[4], vf1[4];
#pragma unroll
        for (int s = 0; s < 4; ++s) {
          const int sl0 = (8 * hf) | ((2 * s + cH) ^ (l31 & 7));
          vf0[s] = *(const bf16x8*)(VSb + l31 * 128 + sl0 * 8);
          vf1[s] = *(const bf16x8*)(VSb + (32 + l31) * 128 + sl0 * 8);
        }

        // PV: B-frag via pack + one xor-32 swap per k-step
#pragma unroll
        for (int s = 0; s < 4; ++s) {
          const int kvt = s >> 1;
          const int rq_own = 2 * (s & 1) + cH;
          const int rq_snd = 2 * (s & 1) + 1 - cH;
          const uint32_t own0 = pk[kvt][rq_own][0], own1 = pk[kvt][rq_own][1];
          const uint32_t rcv0 = (uint32_t)__shfl_xor((int)pk[kvt][rq_snd][0], 32, 64);
          const uint32_t rcv1 = (uint32_t)__shfl_xor((int)pk[kvt][rq_snd][1], 32, 64);
          union { uint32_t u[4]; bf16x8 v; } pf;
          pf.u[0] = cH ? rcv0 : own0;
          pf.u[1] = cH ? rcv1 : own1;
          pf.u[2] = cH ? own0 : rcv0;
          pf.u[3] = cH ? own1 : rcv1;
          o0 = MFMA32(vf0[s], pf.v, o0);
          o1 = MFMA32(vf1[s], pf.v, o1);
        }
      }
    }

    // split-kv merge: half1 writes (o, sum) to LDS; half0 combines and stores y
    __syncthreads();
    float4* Msh = (float4*)smem;
    float* Ls2 = (float*)(smem + 65536);
    const float stot = lsum + __shfl_xor(lsum, 32, 64);
    union { f32x16 v; float4 q4[4]; } u0, u1;
    u0.v = o0; u1.v = o1;
    if (hf == 1) {
#pragma unroll
      for (int i = 0; i < 4; ++i) {
        Msh[(i * 4 + wq) * 64 + l] = u0.q4[i];
        Msh[((i + 4) * 4 + wq) * 64 + l] = u1.q4[i];
      }
      Ls2[wq * 64 + l] = stot;
    }
    __syncthreads();
    if (hf == 0) {
#pragma unroll
      for (int i = 0; i < 4; ++i) {
        float4 a = Msh[(i * 4 + wq) * 64 + l];
        float4 b2 = Msh[((i + 4) * 4 + wq) * 64 + l];
        u0.q4[i].x += a.x; u0.q4[i].y += a.y; u0.q4[i].z += a.z; u0.q4[i].w += a.w;
        u1.q4[i].x += b2.x; u1.q4[i].y += b2.y; u1.q4[i].z += b2.z; u1.q4[i].w += b2.w;
      }
      const float inv = 1.0f / (stot + Ls2[wq * 64 + l]);
      __bf16* yrow = yb + ((size_t)(bb * 2048 + q)) * 1024 + h * 64;
#pragma unroll
      for (int dt = 0; dt < 2; ++dt) {
        const f32x16& o = dt ? u1.v : u0.v;
#pragma unroll
        for (int rq = 0; rq < 4; ++rq) {
          __bf16 ov[4];
#pragma unroll
          for (int i = 0; i < 4; ++i) ov[i] = (__bf16)(o[4 * rq + i] * inv);
          *(uint2*)(yrow + dt * 32 + 8 * rq + 4 * cH) = *(uint2*)ov;
        }
      }
    }
  }
}

// ---------------- GEMM2: out = y @ W_proj + b_proj (fp32 out) ----------------
__global__ __launch_bounds__(256) void k_gemm_proj(
    const __bf16* __restrict__ A, const __bf16* __restrict__ Bt,
    const float* __restrict__ bias, float* __restrict__ out) {
  __shared__ __align__(16) __bf16 As[128 * 32];
  __shared__ __align__(16) __bf16 Bs[128 * 32];
  const int tid = threadIdx.x;
  const int w = tid >> 6, l = tid & 63;
  const int l15 = l & 15, quad = l >> 4;
  const int wr = w >> 1, wc = w & 1;
  const int bm0 = blockIdx.y * 128, bn0 = blockIdx.x * 128;

  const int rs = w * 32 + (l >> 2);
  const int kc = (l & 3) * 8;
  const __bf16* gA = A + (size_t)(bm0 + rs) * 1024 + kc;
  const __bf16* gB = Bt + (size_t)(bn0 + rs) * 1024 + kc;

  f32x4 acc[4][4] = {};

  for (int k0 = 0; k0 < 1024; k0 += 32) {
    gload_lds16(gA + k0,             As + w * 1024);
    gload_lds16(gA + k0 + 16 * 1024, As + w * 1024 + 512);
    gload_lds16(gB + k0,             Bs + w * 1024);
    gload_lds16(gB + k0 + 16 * 1024, Bs + w * 1024 + 512);
    __syncthreads();
    bf16x8 af[4], bv[4];
#pragma unroll
    for (int mt = 0; mt < 4; ++mt)
      af[mt] = *(const bf16x8*)(As + (wr * 64 + mt * 16 + l15) * 32 + quad * 8);
#pragma unroll
    for (int nt = 0; nt < 4; ++nt)
      bv[nt] = *(const bf16x8*)(Bs + (wc * 64 + nt * 16 + l15) * 32 + quad * 8);
#pragma unroll
    for (int mt = 0; mt < 4; ++mt)
#pragma unroll
      for (int nt = 0; nt < 4; ++nt)
        acc[mt][nt] = MFMA16(af[mt], bv[nt], acc[mt][nt]);
    __syncthreads();
  }

#pragma unroll
  for (int nt = 0; nt < 4; ++nt) {
    const int n = bn0 + wc * 64 + nt * 16 + l15;
    const float bvv = bias[n];
#pragma unroll
    for (int mt = 0; mt < 4; ++mt) {
#pragma unroll
      for (int r = 0; r < 4; ++r) {
        const int m = bm0 + wr * 64 + mt * 16 + quad * 4 + r;
        out[(size_t)m * 1024 + n] = acc[mt][nt][r] + bvv;
      }
    }
  }
}

extern "C" void kernel_launch(void* const* d_in, const int* in_sizes, int n_in,
                              void* d_out, int out_size, void* d_ws, size_t ws_size,
                              hipStream_t stream) {
  const float* x      = (const float*)d_in[0];
  const float* W_attn = (const float*)d_in[1];
  const float* b_attn = (const float*)d_in[2];
  const float* W_proj = (const float*)d_in[3];
  const float* b_proj = (const float*)d_in[4];
  float* out = (float*)d_out;
  char* ws = (char*)d_ws;

  __bf16* xb  = (__bf16*)(ws);                     // 16 MiB  x bf16; later reused as y
  __bf16* WaT = (__bf16*)(ws + (16ull << 20));     //  6 MiB  W_attn^T bf16
  __bf16* WpT = (__bf16*)(ws + (22ull << 20));     //  2 MiB  W_proj^T bf16
  __bf16* Qg  = (__bf16*)(ws + (24ull << 20));     // 16 MiB  Q*SC [bh][T][64]
  __bf16* Kg  = (__bf16*)(ws + (40ull << 20));     // 16 MiB  K [bh][T][64]
  __bf16* VTg = (__bf16*)(ws + (56ull << 20));     // 16 MiB  V^T [bh][64][T]

  k_cvt<<<8192, 256, 0, stream>>>(x, xb, 2097152);
  k_transpose<<<dim3(96, 32), 256, 0, stream>>>(W_attn, WaT, 1024, 3072);
  k_transpose<<<dim3(32, 32), 256, 0, stream>>>(W_proj, WpT, 1024, 1024);
  k_gemm_qkv<<<dim3(24, 64), 256, 0, stream>>>(xb, WaT, b_attn, Qg, Kg, VTg);
  k_attn<<<dim3(64, 8), 512, 0, stream>>>(Qg, Kg, VTg, xb /* y reuses xb */);
  k_gemm_proj<<<dim3(8, 64), 256, 0, stream>>>(xb, WpT, b_proj, out);
}

// Round 7
// 256.875 us; speedup vs baseline: 1.3764x; 1.2360x over previous
//
#include <hip/hip_runtime.h>
#include <cstdint>

// Problem constants: B=4, T=2048, D=1024, H=16, hd=64
#define MFMA16(a, b, c) __builtin_amdgcn_mfma_f32_16x16x32_bf16(a, b, c, 0, 0, 0)
#define MFMA32(a, b, c) __builtin_amdgcn_mfma_f32_32x32x16_bf16(a, b, c, 0, 0, 0)

typedef float  f32x4   __attribute__((ext_vector_type(4)));
typedef float  f32x16  __attribute__((ext_vector_type(16)));
typedef __bf16 bf16x8  __attribute__((ext_vector_type(8)));
typedef short  s16x4   __attribute__((ext_vector_type(4)));
typedef __bf16 bf16x4  __attribute__((ext_vector_type(4)));

// ---- K=8 MFMA for the PV stage: B-fragment (k = 4*cH + j) matches the S-tile
// C-layout rows per lane exactly -> no cross-lane P transform needed at all.
#if __has_builtin(__builtin_amdgcn_mfma_f32_32x32x8bf16_1k)
#define HAVE_MFMA8 1
__device__ __forceinline__ f32x16 MFMA8(uint32_t a0, uint32_t a1,
                                        uint32_t b0, uint32_t b1, f32x16 c) {
  union { uint32_t u[2]; s16x4 v; } ua, ub;
  ua.u[0] = a0; ua.u[1] = a1; ub.u[0] = b0; ub.u[1] = b1;
  return __builtin_amdgcn_mfma_f32_32x32x8bf16_1k(ua.v, ub.v, c, 0, 0, 0);
}
#elif __has_builtin(__builtin_amdgcn_mfma_f32_32x32x8_bf16)
#define HAVE_MFMA8 1
__device__ __forceinline__ f32x16 MFMA8(uint32_t a0, uint32_t a1,
                                        uint32_t b0, uint32_t b1, f32x16 c) {
  union { uint32_t u[2]; bf16x4 v; } ua, ub;
  ua.u[0] = a0; ua.u[1] = a1; ub.u[0] = b0; ub.u[1] = b1;
  return __builtin_amdgcn_mfma_f32_32x32x8_bf16(ua.v, ub.v, c, 0, 0, 0);
}
#else
#define HAVE_MFMA8 0
#endif

__device__ __forceinline__ void gload_lds16(const void* g, const void* l) {
  __builtin_amdgcn_global_load_lds(
      (const __attribute__((address_space(1))) unsigned int*)(uintptr_t)g,
      (__attribute__((address_space(3))) unsigned int*)(unsigned int)(uintptr_t)l,
      16, 0, 0);
}

__device__ __forceinline__ uint32_t pack_bf16(float a, float b) {
  union { __bf16 h[2]; uint32_t u; } u;
  u.h[0] = (__bf16)a; u.h[1] = (__bf16)b;
  return u.u;
}

__device__ __forceinline__ float fexp2(float x) { return __builtin_amdgcn_exp2f(x); }

// ---------------- fp32 -> bf16 convert (vectorized) ----------------
__global__ void k_cvt(const float* __restrict__ in, __bf16* __restrict__ out, int n4) {
  int i = blockIdx.x * 256 + threadIdx.x;
  if (i >= n4) return;
  float4 v = reinterpret_cast<const float4*>(in)[i];
  __bf16 o[4] = {(__bf16)v.x, (__bf16)v.y, (__bf16)v.z, (__bf16)v.w};
  *reinterpret_cast<uint2*>(out + (size_t)i * 4) = *reinterpret_cast<const uint2*>(o);
}

// ---------------- fp32 [R][C] -> bf16 [C][R] tiled transpose ----------------
__global__ void k_transpose(const float* __restrict__ in, __bf16* __restrict__ out,
                            int R, int C) {
  __shared__ float tile[32][33];
  const int c0 = blockIdx.x * 32, r0 = blockIdx.y * 32;
  const int x = threadIdx.x & 31, y = threadIdx.x >> 5;
#pragma unroll
  for (int i = 0; i < 4; ++i)
    tile[y + i * 8][x] = in[(size_t)(r0 + y + i * 8) * C + c0 + x];
  __syncthreads();
#pragma unroll
  for (int i = 0; i < 4; ++i)
    out[(size_t)(c0 + y + i * 8) * R + r0 + x] = (__bf16)tile[x][y + i * 8];
}

// ---------------- GEMM1: qkv = x @ W_attn + b_attn, scattered to Q/K/VT ----------------
// Q pre-scaled by (1/sqrt(64))*log2(e). blockIdx.x>>3 selects output: 0=Q 1=K 2=V.
// All epilogues go through LDS -> fully coalesced 16B stores.
__global__ __launch_bounds__(256) void k_gemm_qkv(
    const __bf16* __restrict__ A, const __bf16* __restrict__ Bt,
    const float* __restrict__ bias,
    __bf16* __restrict__ Qg, __bf16* __restrict__ Kg, __bf16* __restrict__ VTg) {
  __shared__ __align__(16) char GS[16384];
  __bf16* As = (__bf16*)GS;
  __bf16* Bs = (__bf16*)(GS + 8192);
  const int tid = threadIdx.x;
  const int w = tid >> 6, l = tid & 63;
  const int l15 = l & 15, quad = l >> 4;
  const int wr = w >> 1, wc = w & 1;
  const int bm0 = blockIdx.y * 128, bn0 = blockIdx.x * 128;
  const int which = blockIdx.x >> 3;  // 0 Q, 1 K, 2 V (block-uniform)
  const float SC = 0.18033688011112042f;

  const int rs = w * 32 + (l >> 2);
  const int kc = (l & 3) * 8;
  const __bf16* gA = A + (size_t)(bm0 + rs) * 1024 + kc;
  const __bf16* gB = Bt + (size_t)(bn0 + rs) * 1024 + kc;

  f32x4 acc[4][4] = {};

  for (int k0 = 0; k0 < 1024; k0 += 32) {
    gload_lds16(gA + k0,             As + w * 1024);
    gload_lds16(gA + k0 + 16 * 1024, As + w * 1024 + 512);
    gload_lds16(gB + k0,             Bs + w * 1024);
    gload_lds16(gB + k0 + 16 * 1024, Bs + w * 1024 + 512);
    __syncthreads();
    bf16x8 af[4], bv[4];
#pragma unroll
    for (int mt = 0; mt < 4; ++mt)
      af[mt] = *(const bf16x8*)(As + (wr * 64 + mt * 16 + l15) * 32 + quad * 8);
#pragma unroll
    for (int nt = 0; nt < 4; ++nt)
      bv[nt] = *(const bf16x8*)(Bs + (wc * 64 + nt * 16 + l15) * 32 + quad * 8);
#pragma unroll
    for (int mt = 0; mt < 4; ++mt)
#pragma unroll
      for (int nt = 0; nt < 4; ++nt)
        acc[mt][nt] = MFMA16(af[mt], bv[nt], acc[mt][nt]);
    __syncthreads();
  }

  if (which < 2) {
    // Q/K epilogue: per-wave LDS transpose-lite (row stride 160B, 2-way max
    // bank aliasing = free) -> 16B coalesced global stores.
    __bf16* dst = which == 0 ? Qg : Kg;
    const float mul = which == 0 ? SC : 1.0f;
    __bf16* TR = (__bf16*)GS + w * 1280;  // 2560 B per wave (16 rows x 160 B)
    const int hh = ((bn0 + wc * 64) & 1023) >> 6;
    const int m0 = bm0 + wr * 64;
    const int bbq = m0 >> 11;
    float bv4[4];
#pragma unroll
    for (int nt = 0; nt < 4; ++nt) bv4[nt] = bias[bn0 + wc * 64 + nt * 16 + l15];
    const int row = l >> 2, cc = l & 3;
#pragma unroll
    for (int mt = 0; mt < 4; ++mt) {
#pragma unroll
      for (int nt = 0; nt < 4; ++nt)
#pragma unroll
        for (int r = 0; r < 4; ++r)
          TR[(quad * 4 + r) * 80 + nt * 16 + l15] =
              (__bf16)((acc[mt][nt][r] + bv4[nt]) * mul);
      __asm__ volatile("s_waitcnt lgkmcnt(0)" ::: "memory");
      uint4 v0 = *(const uint4*)(TR + row * 80 + cc * 8);
      uint4 v1 = *(const uint4*)(TR + row * 80 + cc * 8 + 32);
      const int t = (m0 & 2047) + mt * 16 + row;
      __bf16* gp = dst + (((size_t)(bbq * 16 + hh)) * 2048 + t) * 64 + cc * 8;
      *(uint4*)gp = v0;
      *(uint4*)(gp + 32) = v1;
      __asm__ volatile("" ::: "memory");  // keep TR reuse ordered across mt
    }
  } else {
    // V: LDS transpose. VLs: [64 n_local][32 m-chunks of 8B, XOR-swizzled]
    __bf16* VLs = (__bf16*)GS;
    const int bbq = bm0 >> 11;
    const int tloc = bm0 & 2047;
#pragma unroll
    for (int h2 = 0; h2 < 2; ++h2) {
      __syncthreads();
      if (wc == h2) {
#pragma unroll
        for (int nt = 0; nt < 4; ++nt) {
          const int nl = nt * 16 + l15;
          const float bvv = bias[bn0 + wc * 64 + nt * 16 + l15];
#pragma unroll
          for (int mt = 0; mt < 4; ++mt) {
            const int cm = wr * 16 + mt * 4 + quad;
            const int cs = (cm & 16) | ((cm & 15) ^ l15);
            uint2 pkv;
            pkv.x = pack_bf16(acc[mt][nt][0] + bvv, acc[mt][nt][1] + bvv);
            pkv.y = pack_bf16(acc[mt][nt][2] + bvv, acc[mt][nt][3] + bvv);
            *(uint2*)(VLs + nl * 128 + cs * 4) = pkv;
          }
        }
      }
      __syncthreads();
      const int nl = tid >> 2;
      const int ng = bn0 + h2 * 64 + nl;
      const int v = ng - 2048;
      const int bhd = bbq * 16 + (v >> 6), dh = v & 63;
      __bf16* vrow = VTg + ((size_t)bhd * 64 + dh) * 2048;
#pragma unroll
      for (int p2 = 0; p2 < 4; ++p2) {
        const int c16 = (tid & 3) + p2 * 4;
        const int g0 = 2 * c16, g1 = g0 + 1;
        const int s0 = (g0 & 16) | ((g0 & 15) ^ (nl & 15));
        const int s1 = (g1 & 16) | ((g1 & 15) ^ (nl & 15));
        uint2 a = *(const uint2*)(VLs + nl * 128 + s0 * 4);
        uint2 b = *(const uint2*)(VLs + nl * 128 + s1 * 4);
        uint4 val = {a.x, a.y, b.x, b.y};
        *(uint4*)(vrow + tloc + c16 * 8) = val;
      }
    }
  }
}

// ---------------- Flash attention: 8 waves, split-kv, 32x32 MFMA ----------------
// Grid (64, 8), 512 threads. Block handles q-tiles {p, 15-p} for bh=blockIdx.x.
// Waves: wq = w&3 (q sub-tile of 32 rows), hf = w>>2 (kv half). Each barrier
// interval stages 128 kv rows; half hf computes tile 2j+hf.
// Fixed-max softmax (exact by shift-invariance); PV via K=8 MFMA: the packed
// P dwords ARE the B-fragment (k = 4cH+j) -> zero cross-lane transform.
__global__ __launch_bounds__(512) void k_attn(
    const __bf16* __restrict__ Qg, const __bf16* __restrict__ Kg,
    const __bf16* __restrict__ VTg, __bf16* __restrict__ yb) {
  __shared__ __align__(16) char smem[66560];
  const int tid = threadIdx.x;
  const int w = tid >> 6, l = tid & 63;
  const int wq = w & 3, hf = w >> 2, wqh = wq >> 1;
  const int l31 = l & 31, cH = l >> 5;
  const int bh = blockIdx.x;
  const int bb = bh >> 4, h = bh & 15;
  const __bf16* Qb = Qg + (size_t)bh * 2048 * 64;

  // staging addresses
  const int rk = w * 8 + (l >> 3);
  const __bf16* gK = Kg + ((size_t)bh * 2048 + rk) * 64 + (((l & 7) ^ (rk & 7)) * 8);
  const int rv = w * 4 + (l >> 4);
  const int rvB = rv + 32;
  const __bf16* gVA = VTg + ((size_t)bh * 64 + rv) * 2048 +
                      (((l & 8) | ((l & 7) ^ (rv & 7))) * 8);
  const __bf16* gVB = VTg + ((size_t)bh * 64 + rvB) * 2048 +
                      (((l & 8) | ((l & 7) ^ (rvB & 7))) * 8);

  // lane-constant LDS read offsets (bytes), hoisted out of the k-loop
  const int R0 = 64 * hf + l31;
  int koff[4], koff1[4];
#pragma unroll
  for (int s = 0; s < 4; ++s) {
    koff[s]  = R0 * 64 * 2 + (((2 * s + cH) ^ (R0 & 7)) * 16);
    koff1[s] = (R0 + 32) * 64 * 2 + (((2 * s + cH) ^ (R0 & 7)) * 16);
  }
#if HAVE_MFMA8
  int voff[2][4], voff1[2][4];
#pragma unroll
  for (int kvt = 0; kvt < 2; ++kvt)
#pragma unroll
    for (int g = 0; g < 4; ++g) {
      const int slot = (8 * hf) | ((4 * kvt + g) ^ (l31 & 7));
      voff[kvt][g]  = l31 * 256 + slot * 16 + 8 * cH;
      voff1[kvt][g] = (32 + l31) * 256 + slot * 16 + 8 * cH;
    }
#else
  int voffL[4], voffL1[4];
#pragma unroll
  for (int s = 0; s < 4; ++s) {
    const int sl0 = (8 * hf) | ((2 * s + cH) ^ (l31 & 7));
    voffL[s]  = l31 * 256 + sl0 * 16;
    voffL1[s] = (32 + l31) * 256 + sl0 * 16;
  }
#endif

  for (int seg = 0; seg < 2; ++seg) {
    const int p = seg ? 15 - blockIdx.y : blockIdx.y;
    const int qt0 = p * 128 + wq * 32;
    const int q = qt0 + l31;

    __syncthreads();

    bf16x8 qf[4];
#pragma unroll
    for (int s = 0; s < 4; ++s)
      qf[s] = *(const bf16x8*)(Qb + (size_t)q * 64 + s * 16 + cH * 8);

    f32x16 o0 = {}, o1 = {};
    float lsum = 0.f;

    {
      char* KSb = smem;
      char* VSb = smem + 32768;
      gload_lds16(gK,           KSb + w * 1024);
      gload_lds16(gK + 64 * 64, KSb + 8192 + w * 1024);
      gload_lds16(gVA,          VSb + w * 1024);
      gload_lds16(gVB,          VSb + 8192 + w * 1024);
    }

    for (int j = 0; j <= p; ++j) {
      __syncthreads();
      if (j < p) {
        const int b2 = (j + 1) & 1;
        char* KSb = smem + b2 * 16384;
        char* VSb = smem + 32768 + b2 * 16384;
        const size_t ko = (size_t)(128 * (j + 1)) * 64;
        gload_lds16(gK + ko,             KSb + w * 1024);
        gload_lds16(gK + ko + 64 * 64,   KSb + 8192 + w * 1024);
        gload_lds16(gVA + 128 * (j + 1), VSb + w * 1024);
        gload_lds16(gVB + 128 * (j + 1), VSb + 8192 + w * 1024);
      }
      const bool act = (j < p) || (hf <= wqh);
      if (act) {
        const bool diag = (j == p) && (hf == wqh);
        const char* KSb = smem + (j & 1) * 16384;
        const char* VSb = smem + 32768 + (j & 1) * 16384;
        const int kv0 = (2 * j + hf) * 64;

        bf16x8 kf0[4], kf1[4];
#pragma unroll
        for (int s = 0; s < 4; ++s) {
          kf0[s] = *(const bf16x8*)(KSb + koff[s]);
          kf1[s] = *(const bf16x8*)(KSb + koff1[s]);
        }
        f32x16 st0 = {}, st1 = {};
#pragma unroll
        for (int s = 0; s < 4; ++s) st0 = MFMA32(kf0[s], qf[s], st0);
#pragma unroll
        for (int s = 0; s < 4; ++s) st1 = MFMA32(kf1[s], qf[s], st1);

        if (diag) {
          const int base0 = kv0 + 4 * cH;
          const int base1 = kv0 + 32 + 4 * cH;
#pragma unroll
          for (int r = 0; r < 16; ++r) {
            const int off = (r & 3) + 8 * (r >> 2);
            if (base0 + off > q) st0[r] = -1e30f;
            if (base1 + off > q) st1[r] = -1e30f;
          }
        }

        // exp2 (fixed max 0), pairwise-tree sum, pack to bf16 dwords
        uint32_t pk[2][4][2];
        float sacc[2];
#pragma unroll
        for (int kvt = 0; kvt < 2; ++kvt) {
          float pp[16];
#pragma unroll
          for (int r = 0; r < 16; ++r) pp[r] = fexp2(kvt ? st1[r] : st0[r]);
          float s01 = (pp[0] + pp[1]) + (pp[2] + pp[3]);
          float s23 = (pp[4] + pp[5]) + (pp[6] + pp[7]);
          float s45 = (pp[8] + pp[9]) + (pp[10] + pp[11]);
          float s67 = (pp[12] + pp[13]) + (pp[14] + pp[15]);
          sacc[kvt] = (s01 + s23) + (s45 + s67);
#pragma unroll
          for (int rq = 0; rq < 4; ++rq) {
            pk[kvt][rq][0] = pack_bf16(pp[4 * rq], pp[4 * rq + 1]);
            pk[kvt][rq][1] = pack_bf16(pp[4 * rq + 2], pp[4 * rq + 3]);
          }
        }
        lsum += sacc[0] + sacc[1];

#if HAVE_MFMA8
        // PV: K=8 MFMA, pk dwords are the B-fragment directly (no shuffles)
#pragma unroll
        for (int kvt = 0; kvt < 2; ++kvt)
#pragma unroll
          for (int g = 0; g < 4; ++g) {
            const uint2 va = *(const uint2*)(VSb + voff[kvt][g]);
            const uint2 vb = *(const uint2*)(VSb + voff1[kvt][g]);
            o0 = MFMA8(va.x, va.y, pk[kvt][g][0], pk[kvt][g][1], o0);
            o1 = MFMA8(vb.x, vb.y, pk[kvt][g][0], pk[kvt][g][1], o1);
          }
#else
        // fallback: K=16 MFMA with bpermute-based B-fragment assembly
        bf16x8 vf0[4], vf1[4];
#pragma unroll
        for (int s = 0; s < 4; ++s) {
          vf0[s] = *(const bf16x8*)(VSb + voffL[s]);
          vf1[s] = *(const bf16x8*)(VSb + voffL1[s]);
        }
#pragma unroll
        for (int s = 0; s < 4; ++s) {
          const int kvt = s >> 1;
          const int rq_own = 2 * (s & 1) + cH;
          const int rq_snd = 2 * (s & 1) + 1 - cH;
          const uint32_t own0 = pk[kvt][rq_own][0], own1 = pk[kvt][rq_own][1];
          const uint32_t rcv0 = (uint32_t)__shfl_xor((int)pk[kvt][rq_snd][0], 32, 64);
          const uint32_t rcv1 = (uint32_t)__shfl_xor((int)pk[kvt][rq_snd][1], 32, 64);
          union { uint32_t u[4]; bf16x8 v; } pf;
          pf.u[0] = cH ? rcv0 : own0;
          pf.u[1] = cH ? rcv1 : own1;
          pf.u[2] = cH ? own0 : rcv0;
          pf.u[3] = cH ? own1 : rcv1;
          o0 = MFMA32(vf0[s], pf.v, o0);
          o1 = MFMA32(vf1[s], pf.v, o1);
        }
#endif
      }
    }

    // split-kv merge: half1 writes (o, sum) to LDS; half0 combines and stores y
    __syncthreads();
    float4* Msh = (float4*)smem;
    float* Ls2 = (float*)(smem + 65536);
    const float stot = lsum + __shfl_xor(lsum, 32, 64);
    union { f32x16 v; float4 q4[4]; } u0, u1;
    u0.v = o0; u1.v = o1;
    if (hf == 1) {
#pragma unroll
      for (int i = 0; i < 4; ++i) {
        Msh[(i * 4 + wq) * 64 + l] = u0.q4[i];
        Msh[((i + 4) * 4 + wq) * 64 + l] = u1.q4[i];
      }
      Ls2[wq * 64 + l] = stot;
    }
    __syncthreads();
    if (hf == 0) {
#pragma unroll
      for (int i = 0; i < 4; ++i) {
        float4 a = Msh[(i * 4 + wq) * 64 + l];
        float4 b2 = Msh[((i + 4) * 4 + wq) * 64 + l];
        u0.q4[i].x += a.x; u0.q4[i].y += a.y; u0.q4[i].z += a.z; u0.q4[i].w += a.w;
        u1.q4[i].x += b2.x; u1.q4[i].y += b2.y; u1.q4[i].z += b2.z; u1.q4[i].w += b2.w;
      }
      const float inv = 1.0f / (stot + Ls2[wq * 64 + l]);
      __bf16* yrow = yb + ((size_t)(bb * 2048 + q)) * 1024 + h * 64;
#pragma unroll
      for (int dt = 0; dt < 2; ++dt) {
        const f32x16& o = dt ? u1.v : u0.v;
#pragma unroll
        for (int rq = 0; rq < 4; ++rq) {
          __bf16 ov[4];
#pragma unroll
          for (int i = 0; i < 4; ++i) ov[i] = (__bf16)(o[4 * rq + i] * inv);
          *(uint2*)(yrow + dt * 32 + 8 * rq + 4 * cH) = *(uint2*)ov;
        }
      }
    }
  }
}

// ---------------- GEMM2: out = y @ W_proj + b_proj (fp32 out) ----------------
__global__ __launch_bounds__(256) void k_gemm_proj(
    const __bf16* __restrict__ A, const __bf16* __restrict__ Bt,
    const float* __restrict__ bias, float* __restrict__ out) {
  __shared__ __align__(16) __bf16 As[128 * 32];
  __shared__ __align__(16) __bf16 Bs[128 * 32];
  const int tid = threadIdx.x;
  const int w = tid >> 6, l = tid & 63;
  const int l15 = l & 15, quad = l >> 4;
  const int wr = w >> 1, wc = w & 1;
  const int bm0 = blockIdx.y * 128, bn0 = blockIdx.x * 128;

  const int rs = w * 32 + (l >> 2);
  const int kc = (l & 3) * 8;
  const __bf16* gA = A + (size_t)(bm0 + rs) * 1024 + kc;
  const __bf16* gB = Bt + (size_t)(bn0 + rs) * 1024 + kc;

  f32x4 acc[4][4] = {};

  for (int k0 = 0; k0 < 1024; k0 += 32) {
    gload_lds16(gA + k0,             As + w * 1024);
    gload_lds16(gA + k0 + 16 * 1024, As + w * 1024 + 512);
    gload_lds16(gB + k0,             Bs + w * 1024);
    gload_lds16(gB + k0 + 16 * 1024, Bs + w * 1024 + 512);
    __syncthreads();
    bf16x8 af[4], bv[4];
#pragma unroll
    for (int mt = 0; mt < 4; ++mt)
      af[mt] = *(const bf16x8*)(As + (wr * 64 + mt * 16 + l15) * 32 + quad * 8);
#pragma unroll
    for (int nt = 0; nt < 4; ++nt)
      bv[nt] = *(const bf16x8*)(Bs + (wc * 64 + nt * 16 + l15) * 32 + quad * 8);
#pragma unroll
    for (int mt = 0; mt < 4; ++mt)
#pragma unroll
      for (int nt = 0; nt < 4; ++nt)
        acc[mt][nt] = MFMA16(af[mt], bv[nt], acc[mt][nt]);
    __syncthreads();
  }

#pragma unroll
  for (int nt = 0; nt < 4; ++nt) {
    const int n = bn0 + wc * 64 + nt * 16 + l15;
    const float bvv = bias[n];
#pragma unroll
    for (int mt = 0; mt < 4; ++mt) {
#pragma unroll
      for (int r = 0; r < 4; ++r) {
        const int m = bm0 + wr * 64 + mt * 16 + quad * 4 + r;
        out[(size_t)m * 1024 + n] = acc[mt][nt][r] + bvv;
      }
    }
  }
}

extern "C" void kernel_launch(void* const* d_in, const int* in_sizes, int n_in,
                              void* d_out, int out_size, void* d_ws, size_t ws_size,
                              hipStream_t stream) {
  const float* x      = (const float*)d_in[0];
  const float* W_attn = (const float*)d_in[1];
  const float* b_attn = (const float*)d_in[2];
  const float* W_proj = (const float*)d_in[3];
  const float* b_proj = (const float*)d_in[4];
  float* out = (float*)d_out;
  char* ws = (char*)d_ws;

  __bf16* xb  = (__bf16*)(ws);                     // 16 MiB  x bf16; later reused as y
  __bf16* WaT = (__bf16*)(ws + (16ull << 20));     //  6 MiB  W_attn^T bf16
  __bf16* WpT = (__bf16*)(ws + (22ull << 20));     //  2 MiB  W_proj^T bf16
  __bf16* Qg  = (__bf16*)(ws + (24ull << 20));     // 16 MiB  Q*SC [bh][T][64]
  __bf16* Kg  = (__bf16*)(ws + (40ull << 20));     // 16 MiB  K [bh][T][64]
  __bf16* VTg = (__bf16*)(ws + (56ull << 20));     // 16 MiB  V^T [bh][64][T]

  k_cvt<<<8192, 256, 0, stream>>>(x, xb, 2097152);
  k_transpose<<<dim3(96, 32), 256, 0, stream>>>(W_attn, WaT, 1024, 3072);
  k_transpose<<<dim3(32, 32), 256, 0, stream>>>(W_proj, WpT, 1024, 1024);
  k_gemm_qkv<<<dim3(24, 64), 256, 0, stream>>>(xb, WaT, b_attn, Qg, Kg, VTg);
  k_attn<<<dim3(64, 8), 512, 0, stream>>>(Qg, Kg, VTg, xb /* y reuses xb */);
  k_gemm_proj<<<dim3(8, 64), 256, 0, stream>>>(xb, WpT, b_proj, out);
}